// Round 1
// baseline (1272.741 us; speedup 1.0000x reference)
//
#include <hip/hip_runtime.h>
#include <cstdint>
#include <cstddef>

#define GLOBAL_AS __attribute__((address_space(1)))
#define LDS_AS    __attribute__((address_space(3)))

typedef __attribute__((ext_vector_type(8))) __bf16 bf16x8;
typedef __attribute__((ext_vector_type(4))) float  f32x4;

static_assert(sizeof(bf16x8) == 16, "bf16x8 must be 16B");

__device__ __forceinline__ void gl2lds16(const void* g, void* l) {
    // async global->LDS, 16B per lane; LDS dest is wave-uniform base + lane*16
    __builtin_amdgcn_global_load_lds((const GLOBAL_AS void*)g, (LDS_AS void*)l, 16, 0, 0);
}

// ---- K0: W_hh fp32 -> bf16 ; bias = b_ih + b_hh ----
__global__ void k_prep(const float* __restrict__ W, const float* __restrict__ b_ih,
                       const float* __restrict__ b_hh, __bf16* __restrict__ Wb,
                       float* __restrict__ bias) {
    int i = blockIdx.x * 256 + threadIdx.x;  // grid 4096*256 = 1048576 = 1024*1024
    Wb[i] = (__bf16)W[i];
    if (i < 1024) bias[i] = b_ih[i] + b_hh[i];
}

// ---- K1a: M = Bw @ Bw^T (64x64), Bw is (64,1024) ----
__global__ void k_gram(const float* __restrict__ Bw, float* __restrict__ M) {
    int p = blockIdx.x * 256 + threadIdx.x;  // 16 blocks -> 4096 pairs
    int i = p >> 6, j = p & 63;
    const float4* a = (const float4*)(Bw + (size_t)i * 1024);
    const float4* b = (const float4*)(Bw + (size_t)j * 1024);
    float acc = 0.f;
    for (int t = 0; t < 256; ++t) {
        float4 av = a[t], bv = b[t];
        acc += av.x * bv.x + av.y * bv.y + av.z * bv.z + av.w * bv.w;
    }
    M[p] = acc;
}

// ---- K1b: Minv = inv(M), Gauss-Jordan (M is SPD, strongly diag-dominant) ----
__global__ void k_inv(const float* __restrict__ M, float* __restrict__ Minv) {
    __shared__ float aug[64][130];
    __shared__ float fcol[64];
    int tid = threadIdx.x;
    for (int p = tid; p < 4096; p += 256) {
        int r = p >> 6, c = p & 63;
        aug[r][c] = M[p];
        aug[r][64 + c] = (r == c) ? 1.0f : 0.0f;
    }
    __syncthreads();
    for (int p = 0; p < 64; ++p) {
        float rp = 1.0f / aug[p][p];
        __syncthreads();
        if (tid < 128) aug[p][tid] *= rp;
        __syncthreads();
        if (tid < 64) fcol[tid] = aug[tid][p];
        __syncthreads();
        for (int q = tid; q < 64 * 128; q += 256) {
            int r = q >> 7, c = q & 127;
            if (r != p) aug[r][c] -= fcol[r] * aug[p][c];
        }
        __syncthreads();
    }
    for (int p = tid; p < 4096; p += 256) {
        int r = p >> 6, c = p & 63;
        Minv[p] = aug[r][64 + c];
    }
}

// ---- K2a: T1 = X_reset @ Minv^T  (1024 x 64) ----
// row r = b*16 + s maps to x[b, 64*s, :]
__global__ void k_t1(const float* __restrict__ x, const float* __restrict__ Minv,
                     float* __restrict__ T1) {
    int id = blockIdx.x * 256 + threadIdx.x;  // 256 blocks -> 65536
    int r = id >> 6, xp = id & 63;
    const float* xr = x + ((size_t)(r >> 4) * 1024 + (size_t)(r & 15) * 64) * 64;
    const float* mr = Minv + (size_t)xp * 64;  // Minv[xp][x]
    float acc = 0.f;
    for (int t = 0; t < 64; ++t) acc += xr[t] * mr[t];
    T1[id] = acc;
}

// ---- K2b: H0 = T1 @ Bw  (1024 x 1024), store bf16 ----
__global__ void k_h0(const float* __restrict__ T1, const float* __restrict__ Bw,
                     __bf16* __restrict__ H0) {
    int r = blockIdx.y;
    int z = blockIdx.x * 256 + threadIdx.x;  // grid (4,1024)
    const float* t1 = T1 + (size_t)r * 64;
    float acc = 0.f;
    for (int xp = 0; xp < 64; ++xp) acc += t1[xp] * Bw[(size_t)xp * 1024 + z];
    H0[(size_t)r * 1024 + z] = (__bf16)acc;
}

// ---- K3: one recurrence step: Hout = tanh(Hin @ W^T + bias); also write fp32 out ----
// GEMM: M=N=K=1024, tile 64x64, BK=64, 4 waves, mfma 16x16x32 bf16
__global__ __launch_bounds__(256) void k_step(
    const __bf16* __restrict__ Hin, const __bf16* __restrict__ Wb,
    const float* __restrict__ bias, __bf16* __restrict__ Hout,
    float* __restrict__ out, int kstep) {
    __shared__ __bf16 As[64 * 64];
    __shared__ __bf16 Bs[64 * 64];
    const int tid = threadIdx.x;
    const int w = tid >> 6;        // wave 0..3
    const int lane = tid & 63;
    const int row = lane & 15;
    const int quad = lane >> 4;
    const int bm = blockIdx.x, bn = blockIdx.y;

    // staging map: thread covers LDS bytes [tid*16, +16) => tile row tid/8, col (tid%8)*8
    const int srow = tid >> 3;
    const int scol = (tid & 7) * 8;
    const __bf16* Ag0 = Hin + (size_t)(bm * 64 + srow) * 1024 + scol;
    const __bf16* Bg0 = Wb + (size_t)(bn * 64 + srow) * 1024 + scol;

    f32x4 acc[4] = {{0.f, 0.f, 0.f, 0.f},
                    {0.f, 0.f, 0.f, 0.f},
                    {0.f, 0.f, 0.f, 0.f},
                    {0.f, 0.f, 0.f, 0.f}};

    for (int k0 = 0; k0 < 1024; k0 += 64) {
        gl2lds16(Ag0 + k0,             &As[w * 512]);
        gl2lds16(Ag0 + 32 * 1024 + k0, &As[2048 + w * 512]);
        gl2lds16(Bg0 + k0,             &Bs[w * 512]);
        gl2lds16(Bg0 + 32 * 1024 + k0, &Bs[2048 + w * 512]);
        __syncthreads();  // drains vmcnt before barrier
#pragma unroll
        for (int ks = 0; ks < 64; ks += 32) {
            bf16x8 a = *(const bf16x8*)&As[(w * 16 + row) * 64 + ks + quad * 8];
#pragma unroll
            for (int nt = 0; nt < 4; ++nt) {
                bf16x8 b = *(const bf16x8*)&Bs[(nt * 16 + row) * 64 + ks + quad * 8];
                acc[nt] = __builtin_amdgcn_mfma_f32_16x16x32_bf16(a, b, acc[nt], 0, 0, 0);
            }
        }
        __syncthreads();
    }

    // epilogue: C/D layout col=lane&15, row=quad*4+reg
    const int col0 = bn * 64;
#pragma unroll
    for (int nt = 0; nt < 4; ++nt) {
        const int col = col0 + nt * 16 + row;
        const float bv = bias[col];
#pragma unroll
        for (int i = 0; i < 4; ++i) {
            const int m = bm * 64 + w * 16 + quad * 4 + i;  // H row = b*16 + s
            float v = tanhf(acc[nt][i] + bv);
            const int b_ = m >> 4, s_ = m & 15;
            out[((size_t)b_ * 1024 + (size_t)s_ * 64 + kstep) * 1024 + col] = v;
            Hout[(size_t)m * 1024 + col] = (__bf16)v;
        }
    }
}

extern "C" void kernel_launch(void* const* d_in, const int* in_sizes, int n_in,
                              void* d_out, int out_size, void* d_ws, size_t ws_size,
                              hipStream_t stream) {
    const float* x = (const float*)d_in[0];     // (64,1024,64)
    const float* Bw = (const float*)d_in[1];    // (64,1024)
    const float* W_hh = (const float*)d_in[2];  // (1024,1024)
    const float* b_ih = (const float*)d_in[3];  // (1024,)
    const float* b_hh = (const float*)d_in[4];  // (1024,)
    float* out = (float*)d_out;                 // (64,1024,1024)
    uint8_t* ws = (uint8_t*)d_ws;

    __bf16* Wb = (__bf16*)(ws);                        // 2 MB
    __bf16* H0 = (__bf16*)(ws + (2ull << 20));         // 2 MB
    __bf16* H1 = (__bf16*)(ws + (4ull << 20));         // 2 MB
    float* bias = (float*)(ws + (6ull << 20));         // 4 KB
    float* Mg = (float*)(ws + (6ull << 20) + 4096);    // 16 KB
    float* Minv = (float*)(ws + (6ull << 20) + 20480); // 16 KB
    float* T1 = (float*)(ws + (6ull << 20) + 36864);   // 256 KB

    hipLaunchKernelGGL(k_prep, dim3(4096), dim3(256), 0, stream, W_hh, b_ih, b_hh, Wb, bias);
    hipLaunchKernelGGL(k_gram, dim3(16), dim3(256), 0, stream, Bw, Mg);
    hipLaunchKernelGGL(k_inv, dim3(1), dim3(256), 0, stream, Mg, Minv);
    hipLaunchKernelGGL(k_t1, dim3(256), dim3(256), 0, stream, x, Minv, T1);
    hipLaunchKernelGGL(k_h0, dim3(4, 1024), dim3(256), 0, stream, T1, Bw, H0);

    __bf16* bufs[2] = {H0, H1};
    for (int k = 0; k < 64; ++k) {
        hipLaunchKernelGGL(k_step, dim3(16, 16), dim3(256), 0, stream,
                           bufs[k & 1], Wb, bias, bufs[(k + 1) & 1], out, k);
    }
}